// Round 1
// baseline (399.897 us; speedup 1.0000x reference)
//
#include <hip/hip_runtime.h>

// ---------------------------------------------------------------------------
// HopfieldLayer via 3x MX-fp8 MFMA GEMMs (mfma_scale_f32_16x16x128_f8f6f4,
// uniform scales = 1.0). Softmax folded: GEMM2 stores F = 32*(exp(beta*l)-1)
// in fp8 + fp32 row sums; GEMM3 computes
// out = (colsum + F@xi/32) / (8192 + rowsum/32) with exact fp32 colsum.
// fp8 outputs are packed 4B/lane -> K-permuted layout (sigma within
// 128-chunks) matched by xi8/xit8 prep; dot products are perm-invariant.
//
// R5: all GEMMs moved to the T2+T3+T4+T5 8-wave counted-vmcnt structure
// (guide §5 256^2 template, adapted to fp8 K-tile=128B):
//  - 512 thr / 8 waves (2M x 4N), tile 256x256 (GEMM2) or 128x256 (G1/G3:
//    grid 256 = 1 block/CU; 256^2 would leave half the GPU idle at N=1024).
//  - 4 phases per K-tile (C-quadrant x full K-tile each), raw s_barrier
//    pairs, lgkmcnt(0) before MFMA cluster, setprio(1) around MFMAs,
//    ONE s_waitcnt vmcnt(aR+2) per iteration (never 0 in the loop).
//  - Staging: phase p prefetches exactly the LDS set freed at phase p-1's
//    barrier (A0 after ph2 -> staged ph3; B0 after ph3 -> ph4; next tile's
//    A1/B1 in ph1/ph2 of the next iteration into the other buffer).
//    Tail clamps tile index (in-bounds, never-read) so vmcnt stays uniform.
//  - LDS swizzle at 16B granularity: slot' = slot ^ (row&7). Each 8-lane
//    group hits 8 distinct 16B slots -> conflict-free ds_read_b128
//    (R4's 32B-pair swizzle left 2 lanes/slot per group -> 8.4M conflict cy).
//    global_load_lds keeps linear LDS dest; inverse XOR is applied to the
//    per-lane GLOBAL source address (both-sides-or-neither, same involution).
// ---------------------------------------------------------------------------

typedef __attribute__((ext_vector_type(4))) int int4v;   // 16 fp8 bytes
typedef __attribute__((ext_vector_type(8))) int int8v;   // 32 fp8 bytes
typedef __attribute__((ext_vector_type(4))) float f32x4; // MFMA C/D 16x16

#define NDIM 1024
#define NPAT 8192
#define NROW 8192

__device__ __forceinline__ unsigned f8pack4(float a, float b, float c, float d) {
  int w = __builtin_amdgcn_cvt_pk_fp8_f32(a, b, 0, false);
  w = __builtin_amdgcn_cvt_pk_fp8_f32(c, d, w, true);
  return (unsigned)w;
}
__device__ __forceinline__ unsigned char f8b(float v) {
  return (unsigned char)(__builtin_amdgcn_cvt_pk_fp8_f32(v, v, 0, false) & 0xff);
}
// sigma: original col c (0..127) -> packed byte index (epilogue pack order)
__device__ __forceinline__ int sig(int c) {
  return (c & 64) | ((c & 15) << 2) | ((c >> 4) & 3);
}

__device__ __forceinline__ void gload_lds16(const void* g, void* l) {
  __builtin_amdgcn_global_load_lds(
      (const __attribute__((address_space(1))) unsigned char*)g,
      (__attribute__((address_space(3))) unsigned char*)l,
      16, 0, 0);
}

// --------------------------- prep kernels ----------------------------------

__global__ void cast_f8(const float* __restrict__ in,
                        unsigned* __restrict__ out, float scale, int n4) {
  int i = blockIdx.x * blockDim.x + threadIdx.x;
  if (i < n4) {
    float4 v = ((const float4*)in)[i];
    out[i] = f8pack4(v.x * scale, v.y * scale, v.z * scale, v.w * scale);
  }
}

// xi f32 [8192,1024] -> xi8 fp8(32*xi) [8192,1024] (sigma on d within 128),
// xit8 fp8(32*xi) [1024,8192] (sigma on p within 128), colsum[1024] fp32.
__global__ void xi_prep8(const float* __restrict__ xi,
                         unsigned char* __restrict__ xi8,
                         unsigned char* __restrict__ xit8,
                         float* __restrict__ colsum) {
  __shared__ float t[32][33];
  __shared__ float cs[8][32];
  int tx = threadIdx.x, ty = threadIdx.y;
  int d0 = blockIdx.x * 32, p0 = blockIdx.y * 32;
  int d = d0 + tx;
  int di = (d & ~127) + sig(d & 127);
  float psum = 0.f;
#pragma unroll
  for (int j = 0; j < 32; j += 8) {
    float v = xi[(long)(p0 + ty + j) * NDIM + d];
    t[ty + j][tx] = v;
    psum += v;
    xi8[(long)(p0 + ty + j) * NDIM + di] = f8b(32.f * v);
  }
  cs[ty][tx] = psum;
  __syncthreads();
  if (ty == 0) {
    float s = 0.f;
#pragma unroll
    for (int k = 0; k < 8; ++k) s += cs[k][tx];
    atomicAdd(&colsum[d0 + tx], s);
  }
  int p = p0 + tx;
  int pi = (p & ~127) + sig(p & 127);
#pragma unroll
  for (int j = 0; j < 32; j += 8)
    xit8[(long)(d0 + ty + j) * NPAT + pi] = f8b(32.f * t[tx][ty + j]);
}

// --------------------------- 8-wave fp8 GEMM -------------------------------
// acc[m,n] = sum_k A[m,k]*B[n,k]; A:[M,K] fp8, B:[N,K] fp8, K mult of 128.
// BM x 256 tile, 512 threads (8 waves: wm in {0,1} x wn in {0..3}),
// per-wave output (BM/2) x 64 -> acc[MF][4], MF = BM/32.
// K-tile = 128 bytes; 4 phases/iter, quadrant (mq,nq) per phase.
// MODE 0: store fp8(acc/32) packed u32   [GEMM1: q]
// MODE 1: F=32*(exp(beta*acc/32)-1); store fp8(F) packed + rowsum atomics
// MODE 2: store f32 (acc/1024 + colsum[col]) / (8192 + rowsum[row]/32)

#define STAGE_A(MQ, T, BO)                                                  \
  _Pragma("unroll") for (int R = 0; R < aR; ++R)                            \
      gload_lds16(pA[MQ][R] + ((long)(T) << 7), dA[MQ][R] + (BO));

#define STAGE_B(NQ, T, BO)                                                  \
  _Pragma("unroll") for (int R = 0; R < 2; ++R)                             \
      gload_lds16(pB[NQ][R] + ((long)(T) << 7), dB[NQ][R] + (BO));

#define PHASE(MQ, NQ, STAGE_STMT, DO_VM)                                    \
  {                                                                         \
    const unsigned char* sb = smem + bo;                                    \
    int8v af[MH], bf[2];                                                    \
    _Pragma("unroll") for (int t = 0; t < MH; ++t) {                        \
      int off = arow + ((MQ) * MH + t) * 2048;                              \
      int4v lo = *(const int4v*)(sb + off + sxr);                           \
      int4v hi = *(const int4v*)(sb + off + sxr1);                          \
      af[t] = __builtin_shufflevector(lo, hi, 0, 1, 2, 3, 4, 5, 6, 7);      \
    }                                                                       \
    _Pragma("unroll") for (int u = 0; u < 2; ++u) {                         \
      int off = brow + ((NQ) * 2 + u) * 2048;                               \
      int4v lo = *(const int4v*)(sb + off + sxr);                           \
      int4v hi = *(const int4v*)(sb + off + sxr1);                          \
      bf[u] = __builtin_shufflevector(lo, hi, 0, 1, 2, 3, 4, 5, 6, 7);      \
    }                                                                       \
    STAGE_STMT;                                                             \
    __builtin_amdgcn_s_barrier();                                           \
    asm volatile("s_waitcnt lgkmcnt(0)" ::: "memory");                      \
    __builtin_amdgcn_sched_barrier(0);                                      \
    __builtin_amdgcn_s_setprio(1);                                          \
    _Pragma("unroll") for (int mt = 0; mt < MH; ++mt)                       \
      _Pragma("unroll") for (int nt = 0; nt < 2; ++nt)                      \
        acc[(MQ) * MH + mt][(NQ) * 2 + nt] =                                \
            __builtin_amdgcn_mfma_scale_f32_16x16x128_f8f6f4(               \
                af[mt], bf[nt], acc[(MQ) * MH + mt][(NQ) * 2 + nt], 0, 0,   \
                0, 0x7f7f7f7f, 0, 0x7f7f7f7f);                              \
    __builtin_amdgcn_s_setprio(0);                                          \
    if (DO_VM) asm volatile("s_waitcnt vmcnt(%0)" ::"n"(VM) : "memory");    \
    __builtin_amdgcn_s_barrier();                                           \
    __builtin_amdgcn_sched_barrier(0);                                      \
  }

template <int MODE, int BM>
__launch_bounds__(512, 2)
__global__ void gemm8(const unsigned char* __restrict__ A,
                      const unsigned char* __restrict__ B,
                      void* __restrict__ Cv, int N, int K,
                      const float* __restrict__ beta_ptr,
                      const float* __restrict__ rowsum,
                      const float* __restrict__ colsum,
                      float* __restrict__ rowsum_out) {
  constexpr int MF = BM / 32;      // m-fragments per wave (8 or 4)
  constexpr int MH = MF / 2;       // m-fragments per phase
  constexpr int MH16 = MH * 16;    // contiguous rows per A-set region
  constexpr int aR = BM / 128;     // gload rounds per A-set (2 or 1)
  constexpr int VM = aR + 2;       // loads left in flight at iter end
  constexpr int ABYTES = BM * 128;
  constexpr int BUF = ABYTES + 32768;

  __shared__ unsigned char smem[2 * BUF];

  const int tid = threadIdx.x;
  const int lane = tid & 63;
  const int wm = (tid >> 6) >> 2;
  const int wn = (tid >> 6) & 3;
  const int quad = lane >> 4, ln = lane & 15;

  // XCD-aware swizzle (all grids are multiples of 8 -> bijective)
  const int nwg = gridDim.x;
  int wg = blockIdx.x;
  wg = (wg & 7) * (nwg >> 3) + (wg >> 3);
  const int nbx = N >> 8;
  const long row0 = (long)(wg / nbx) * BM;
  const long col0 = (long)(wg % nbx) * 256;
  const int nkt = K >> 7;

  // ---- staging constants -------------------------------------------------
  // Physical LDS slot sd of row r holds logical 16B chunk sd ^ (r&7).
  // gload dest is linear (base + lane*16); the XOR goes on the global src.
  const int sx = (((tid & 7) ^ ((tid >> 3) & 7)) << 4);
  const int jt = tid >> 3;          // per-thread row index within a round
  const int j0 = (tid >> 6) << 3;   // wave-uniform lane0 row index

  const unsigned char* pA[2][aR]; unsigned char* dA[2][aR];
  const unsigned char* pB[2][2];  unsigned char* dB[2][2];
#pragma unroll
  for (int q = 0; q < 2; ++q) {
#pragma unroll
    for (int R = 0; R < aR; ++R) {
      int j = R * 64 + jt;
      int r = q * MH16 + (j % MH16) + (j / MH16) * (BM / 2);
      int jr0 = R * 64 + j0;
      int r0 = q * MH16 + (jr0 % MH16) + (jr0 / MH16) * (BM / 2);
      pA[q][R] = A + (row0 + r) * (long)K + sx;
      dA[q][R] = smem + r0 * 128;
    }
#pragma unroll
    for (int R = 0; R < 2; ++R) {
      int j = R * 64 + jt;
      int r = q * 32 + (j & 31) + (j >> 5) * 64;
      int jr0 = R * 64 + j0;
      int r0 = q * 32 + (jr0 & 31) + (jr0 >> 5) * 64;
      pB[q][R] = B + (col0 + r) * (long)K + sx;
      dB[q][R] = smem + ABYTES + r0 * 128;
    }
  }

  // ---- fragment-read constants (16B-swizzled, conflict-free) -------------
  const int sxr = (((2 * quad) ^ (ln & 7)) << 4);
  const int sxr1 = sxr ^ 16;
  const int arow = (wm * (BM / 2) + ln) * 128;
  const int brow = ABYTES + (wn * 64 + ln) * 128;

  f32x4 acc[MF][4] = {};

  // prologue: tile0 all 4 sets, then tile1 A-set0/B-set0
  STAGE_A(0, 0, 0); STAGE_B(0, 0, 0); STAGE_A(1, 0, 0); STAGE_B(1, 0, 0);
  STAGE_A(0, 1, BUF); STAGE_B(0, 1, BUF);
  asm volatile("s_waitcnt vmcnt(%0)" ::"n"(VM) : "memory");
  __builtin_amdgcn_s_barrier();
  __builtin_amdgcn_sched_barrier(0);

#pragma unroll 2
  for (int i = 0; i < nkt; ++i) {
    const int bo = (i & 1) * BUF;
    const int nbo = BUF - bo;
    const int t1 = (i + 1 < nkt) ? i + 1 : nkt - 1;  // tail clamp: in-bounds,
    const int t2 = (i + 2 < nkt) ? i + 2 : nkt - 1;  // lands in never-read LDS
    PHASE(0, 0, STAGE_A(1, t1, nbo), false);  // stage A-set1(t+1) -> other buf
    PHASE(0, 1, STAGE_B(1, t1, nbo), false);  // stage B-set1(t+1) -> other buf
    PHASE(1, 0, STAGE_A(0, t2, bo), false);   // A-set0 freed at ph2 barrier
    PHASE(1, 1, STAGE_B(0, t2, bo), true);    // B-set0 freed at ph3; vmcnt(VM)
  }
  asm volatile("s_waitcnt vmcnt(0)" ::: "memory");  // drain before endpgm

  // ---- epilogue. C/D: col = ln (within 16-tile), row = quad*4 + r. -------
  if (MODE == 0) {
    unsigned* C32 = (unsigned*)Cv;
    const float s = 1.0f / 32.0f;
#pragma unroll
    for (int mf = 0; mf < MF; ++mf)
#pragma unroll
      for (int r = 0; r < 4; ++r) {
        long row = row0 + wm * (BM / 2) + mf * 16 + quad * 4 + r;
        unsigned w = f8pack4(acc[mf][0][r] * s, acc[mf][1][r] * s,
                             acc[mf][2][r] * s, acc[mf][3][r] * s);
        C32[row * (N >> 2) + (col0 >> 2) + wn * 16 + ln] = w;
      }
  } else if (MODE == 1) {
    unsigned* C32 = (unsigned*)Cv;
    const float bs = beta_ptr[0] * (1.0f / 32.0f);
#pragma unroll
    for (int mf = 0; mf < MF; ++mf)
#pragma unroll
      for (int r = 0; r < 4; ++r) {
        long row = row0 + wm * (BM / 2) + mf * 16 + quad * 4 + r;
        float e0 = (__expf(bs * acc[mf][0][r]) - 1.0f) * 32.f;
        float e1 = (__expf(bs * acc[mf][1][r]) - 1.0f) * 32.f;
        float e2 = (__expf(bs * acc[mf][2][r]) - 1.0f) * 32.f;
        float e3 = (__expf(bs * acc[mf][3][r]) - 1.0f) * 32.f;
        C32[row * (N >> 2) + (col0 >> 2) + wn * 16 + ln] =
            f8pack4(e0, e1, e2, e3);
        float s = e0 + e1 + e2 + e3;
        s += __shfl_xor(s, 1, 64);
        s += __shfl_xor(s, 2, 64);
        s += __shfl_xor(s, 4, 64);
        s += __shfl_xor(s, 8, 64);
        if (ln == 0) atomicAdd(&rowsum_out[row], s);
      }
  } else {
    float* C = (float*)Cv;
#pragma unroll
    for (int mf = 0; mf < MF; ++mf)
#pragma unroll
      for (int r = 0; r < 4; ++r) {
        long row = row0 + wm * (BM / 2) + mf * 16 + quad * 4 + r;
        float inv = 1.0f / (8192.0f + rowsum[row] * (1.0f / 32.0f));
#pragma unroll
        for (int nf = 0; nf < 4; ++nf) {
          long col = col0 + wn * 64 + nf * 16 + ln;
          C[row * N + col] =
              (acc[mf][nf][r] * (1.0f / 1024.0f) + colsum[col]) * inv;
        }
      }
  }
}

// --------------------------- launch ----------------------------------------

extern "C" void kernel_launch(void* const* d_in, const int* in_sizes, int n_in,
                              void* d_out, int out_size, void* d_ws,
                              size_t ws_size, hipStream_t stream) {
  const float* x    = (const float*)d_in[0];
  const float* wq   = (const float*)d_in[1];
  const float* xi   = (const float*)d_in[2];
  const float* beta = (const float*)d_in[3];
  float* out = (float*)d_out;

  char* ws = (char*)d_ws;
  const size_t MB = 1024 * 1024;
  unsigned char* x8   = (unsigned char*)(ws);             //  8 MiB
  unsigned char* wq8  = (unsigned char*)(ws + 8 * MB);    //  1 MiB
  unsigned char* q8   = (unsigned char*)(ws + 9 * MB);    //  8 MiB
  unsigned char* xi8  = (unsigned char*)(ws + 17 * MB);   //  8 MiB
  unsigned char* xit8 = (unsigned char*)(ws + 25 * MB);   //  8 MiB
  float*         rs   = (float*)(ws + 33 * MB);           // 32 KiB
  float*         csum = (float*)(ws + 33 * MB + 32768);   //  4 KiB
  unsigned char* E8   = (unsigned char*)(ws + 34 * MB);   // 64 MiB

  hipMemsetAsync(rs, 0, 36864, stream);  // rs + colsum

  cast_f8<<<(NROW * NDIM / 4) / 256, 256, 0, stream>>>(
      x, (unsigned*)x8, 1.0f, NROW * NDIM / 4);
  cast_f8<<<(NDIM * NDIM / 4) / 256, 256, 0, stream>>>(
      wq, (unsigned*)wq8, 32.0f, NDIM * NDIM / 4);
  xi_prep8<<<dim3(NDIM / 32, NPAT / 32), dim3(32, 8), 0, stream>>>(
      xi, xi8, xit8, csum);

  // GEMM1: q = x @ wq^T (acc = 32q), store fp8(q) packed. 256 blocks (1/CU).
  gemm8<0, 128><<<(NROW / 128) * (NDIM / 256), 512, 0, stream>>>(
      x8, wq8, q8, NDIM, NDIM, nullptr, nullptr, nullptr, nullptr);

  // GEMM2: F = 32*(exp(beta*q.xi)-1), fp8 packed + rowsums. 1024 blocks.
  gemm8<1, 256><<<(NROW / 256) * (NPAT / 256), 512, 0, stream>>>(
      q8, xi8, E8, NPAT, NDIM, beta, nullptr, nullptr, rs);

  // GEMM3: out = (colsum + F@xi/32) / (8192 + rowsum/32). 256 blocks (1/CU).
  gemm8<2, 128><<<(NROW / 128) * (NDIM / 256), 512, 0, stream>>>(
      E8, xit8, out, NDIM, NPAT, nullptr, rs, csum, nullptr);
}

// Round 2
// 360.492 us; speedup vs baseline: 1.1093x; 1.1093x over previous
//
#include <hip/hip_runtime.h>

// ---------------------------------------------------------------------------
// HopfieldLayer via 3x MX-fp8 MFMA GEMMs (mfma_scale_f32_16x16x128_f8f6f4,
// uniform scales = 1.0). Softmax folded: GEMM2 stores F = 32*(exp(beta*l)-1)
// in fp8 + fp32 row sums; GEMM3 computes
// out = (colsum + F@xi/32) / (8192 + rowsum/32) with exact fp32 colsum.
// fp8 outputs are packed 4B/lane -> K-permuted layout (sigma within
// 128-chunks) matched by xi8/xit8 prep; dot products are perm-invariant.
//
// R6: minimum 2-phase pipeline on the PROVEN R4 geometry (post-mortem of R5:
// 256^2/128KB-LDS dropped to 1 block/CU, killing the cross-block latency
// hiding that gave R4 its 117us; XCD-chunk swizzle tripled FETCH_SIZE).
//  - 128x128 tile, 256 thr / 4 waves (2x2), wave tile 64x64 -- unchanged R4.
//  - LDS 2 x 32KB double buffer -> 64KB/block, still 2 blocks/CU.
//  - Per K-iter: issue global_load_lds of tile t+1 into buf^1 FIRST, then
//    ds_read + 16 MFMA (setprio-wrapped) on buf, then ONE __syncthreads()
//    (drains vmcnt(0)+lgkmcnt(0)+barrier). Half of R4's barriers; stage
//    latency overlaps the MFMA cluster; remainder hidden cross-block.
//  - No XCD swizzle (R4's default dim3 order measured 43MB fetch; R5's
//    chunking measured 135MB).
//  - R4's 32B pair-chunk LDS swizzle (slot = p^(r&3)) kept verbatim: one
//    aligned int8v read per MFMA operand, ~4 cyc/read conflicts (12% tax,
//    attack later if the structure win lands).
// ---------------------------------------------------------------------------

typedef __attribute__((ext_vector_type(8))) int int8v;   // 32 fp8 bytes
typedef __attribute__((ext_vector_type(4))) float f32x4; // MFMA C/D 16x16

#define NDIM 1024
#define NPAT 8192
#define NROW 8192

__device__ __forceinline__ unsigned f8pack4(float a, float b, float c, float d) {
  int w = __builtin_amdgcn_cvt_pk_fp8_f32(a, b, 0, false);
  w = __builtin_amdgcn_cvt_pk_fp8_f32(c, d, w, true);
  return (unsigned)w;
}
__device__ __forceinline__ unsigned char f8b(float v) {
  return (unsigned char)(__builtin_amdgcn_cvt_pk_fp8_f32(v, v, 0, false) & 0xff);
}
// sigma: original col c (0..127) -> packed byte index (epilogue pack order)
__device__ __forceinline__ int sig(int c) {
  return (c & 64) | ((c & 15) << 2) | ((c >> 4) & 3);
}

__device__ __forceinline__ void gload_lds16(const void* g, void* l) {
  __builtin_amdgcn_global_load_lds(
      (const __attribute__((address_space(1))) unsigned char*)g,
      (__attribute__((address_space(3))) unsigned char*)l,
      16, 0, 0);
}

// --------------------------- prep kernels ----------------------------------

__global__ void cast_f8(const float* __restrict__ in,
                        unsigned* __restrict__ out, float scale, int n4) {
  int i = blockIdx.x * blockDim.x + threadIdx.x;
  if (i < n4) {
    float4 v = ((const float4*)in)[i];
    out[i] = f8pack4(v.x * scale, v.y * scale, v.z * scale, v.w * scale);
  }
}

// xi f32 [8192,1024] -> xi8 fp8(32*xi) [8192,1024] (sigma on d within 128),
// xit8 fp8(32*xi) [1024,8192] (sigma on p within 128), colsum[1024] fp32.
__global__ void xi_prep8(const float* __restrict__ xi,
                         unsigned char* __restrict__ xi8,
                         unsigned char* __restrict__ xit8,
                         float* __restrict__ colsum) {
  __shared__ float t[32][33];
  __shared__ float cs[8][32];
  int tx = threadIdx.x, ty = threadIdx.y;
  int d0 = blockIdx.x * 32, p0 = blockIdx.y * 32;
  int d = d0 + tx;
  int di = (d & ~127) + sig(d & 127);
  float psum = 0.f;
#pragma unroll
  for (int j = 0; j < 32; j += 8) {
    float v = xi[(long)(p0 + ty + j) * NDIM + d];
    t[ty + j][tx] = v;
    psum += v;
    xi8[(long)(p0 + ty + j) * NDIM + di] = f8b(32.f * v);
  }
  cs[ty][tx] = psum;
  __syncthreads();
  if (ty == 0) {
    float s = 0.f;
#pragma unroll
    for (int k = 0; k < 8; ++k) s += cs[k][tx];
    atomicAdd(&colsum[d0 + tx], s);
  }
  int p = p0 + tx;
  int pi = (p & ~127) + sig(p & 127);
#pragma unroll
  for (int j = 0; j < 32; j += 8)
    xit8[(long)(d0 + ty + j) * NPAT + pi] = f8b(32.f * t[tx][ty + j]);
}

// --------------------------- fp8 GEMM --------------------------------------
// acc[m,n] = sum_k A[m,k]*B[n,k]; A:[M,K] fp8, B:[N,K] fp8, K mult of 128.
// Block tile 128x128, BK=128B, 256 threads (4 waves 2x2; wave tile 64x64).
// LDS row = 128B = 4 pair-chunks of 32B; pair-chunk p of row r stored at
// pair-slot p^(r&3). Lane (q,ln) operand = one aligned 32B load.
// MODE 0: store fp8(acc/32) packed u32   [GEMM1: q]
// MODE 1: F=32*(exp(beta*acc/32)-1); store fp8(F) packed + rowsum atomics
// MODE 2: store f32 (acc/1024 + colsum[col]) / (8192 + rowsum[row]/32)

template <int MODE>
__launch_bounds__(256, 2)
__global__ void gemm_f8(const unsigned char* __restrict__ A,
                        const unsigned char* __restrict__ B,
                        void* __restrict__ Cv, int N, int K,
                        const float* __restrict__ beta_ptr,
                        const float* __restrict__ rowsum,
                        const float* __restrict__ colsum,
                        float* __restrict__ rowsum_out) {
  __shared__ unsigned char smem[65536];  // 2 x (16KB A + 16KB B)

  const int tid = threadIdx.x;
  const int wave = tid >> 6;
  const int lane = tid & 63;
  const int wm = wave >> 1, wn = wave & 1;
  const int quad = lane >> 4, ln = lane & 15;

  const long row0 = (long)blockIdx.y * 128;
  const long col0 = (long)blockIdx.x * 128;

  // staging: each gload covers 8 rows x 128B; lane -> row lane>>3, slot lane&7.
  // slot s of row r must hold global 16B chunk (((s>>1)^(r&3))<<1)|(s&1)
  const int r_in = lane >> 3;
  const int csl = lane & 7;
  const int cg = ((((csl >> 1) ^ (r_in & 3)) << 1) | (csl & 1));
  const unsigned char* gA[4];
  const unsigned char* gB[4];
  int lA[4], lB[4];  // LDS offsets within one 32KB buffer
#pragma unroll
  for (int p = 0; p < 4; ++p) {
    int grp = wave * 4 + p;
    gA[p] = A + (row0 + grp * 8 + r_in) * (long)K + cg * 16;
    gB[p] = B + (col0 + grp * 8 + r_in) * (long)K + cg * 16;
    lA[p] = grp * 1024;
    lB[p] = 16384 + grp * 1024;
  }

  // fragment addressing: row R = base+t*16+ln -> R&3 == ln&3, so the
  // swizzled pair-slot (quad ^ (R&3)) is tile-independent.
  const int ps = (quad ^ (ln & 3)) * 32;
  const int base_a = (wm * 64 + ln) * 128 + ps;
  const int base_b = 16384 + (wn * 64 + ln) * 128 + ps;

  f32x4 acc[4][4] = {};
  const int nkt = K >> 7;

  // prologue: stage tile 0 into buffer 0
#pragma unroll
  for (int p = 0; p < 4; ++p) gload_lds16(gA[p], smem + lA[p]);
#pragma unroll
  for (int p = 0; p < 4; ++p) gload_lds16(gB[p], smem + lB[p]);
#pragma unroll
  for (int p = 0; p < 4; ++p) { gA[p] += 128; gB[p] += 128; }
  __syncthreads();  // vmcnt(0) + barrier: tile 0 resident

#pragma unroll 2
  for (int kt = 0; kt < nkt; ++kt) {
    const unsigned char* sb = smem + (kt & 1) * 32768;
    unsigned char* sn = smem + ((kt + 1) & 1) * 32768;

    // phase 1: issue next-tile staging FIRST (latency hides under MFMA)
    if (kt + 1 < nkt) {
#pragma unroll
      for (int p = 0; p < 4; ++p) gload_lds16(gA[p], sn + lA[p]);
#pragma unroll
      for (int p = 0; p < 4; ++p) gload_lds16(gB[p], sn + lB[p]);
#pragma unroll
      for (int p = 0; p < 4; ++p) { gA[p] += 128; gB[p] += 128; }
    }

    // phase 2: compute current tile (compiler emits fine-grained lgkmcnt)
    int8v af[4], bfv[4];
#pragma unroll
    for (int t = 0; t < 4; ++t)
      af[t] = *(const int8v*)(sb + base_a + t * 2048);
#pragma unroll
    for (int t = 0; t < 4; ++t)
      bfv[t] = *(const int8v*)(sb + base_b + t * 2048);
    __builtin_amdgcn_s_setprio(1);
#pragma unroll
    for (int mt = 0; mt < 4; ++mt)
#pragma unroll
      for (int nt = 0; nt < 4; ++nt)
        acc[mt][nt] = __builtin_amdgcn_mfma_scale_f32_16x16x128_f8f6f4(
            af[mt], bfv[nt], acc[mt][nt], 0, 0, 0, 0x7f7f7f7f, 0, 0x7f7f7f7f);
    __builtin_amdgcn_s_setprio(0);

    // ONE barrier per K-iter: drains vmcnt(0) (next tile staged) +
    // lgkmcnt(0) + s_barrier (all waves done reading sb before overwrite).
    __syncthreads();
  }

  // epilogue. C/D: col = ln (within 16-tile), row = quad*4 + r.
  if (MODE == 0) {
    unsigned* C32 = (unsigned*)Cv;
    const float s = 1.0f / 32.0f;
#pragma unroll
    for (int mt = 0; mt < 4; ++mt)
#pragma unroll
      for (int r = 0; r < 4; ++r) {
        long row = row0 + wm * 64 + mt * 16 + quad * 4 + r;
        unsigned w = f8pack4(acc[mt][0][r] * s, acc[mt][1][r] * s,
                             acc[mt][2][r] * s, acc[mt][3][r] * s);
        C32[row * (N >> 2) + (col0 >> 2) + wn * 16 + ln] = w;
      }
  } else if (MODE == 1) {
    unsigned* C32 = (unsigned*)Cv;
    const float bs = beta_ptr[0] * (1.0f / 32.0f);
#pragma unroll
    for (int mt = 0; mt < 4; ++mt)
#pragma unroll
      for (int r = 0; r < 4; ++r) {
        long row = row0 + wm * 64 + mt * 16 + quad * 4 + r;
        float e0 = (__expf(bs * acc[mt][0][r]) - 1.0f) * 32.f;
        float e1 = (__expf(bs * acc[mt][1][r]) - 1.0f) * 32.f;
        float e2 = (__expf(bs * acc[mt][2][r]) - 1.0f) * 32.f;
        float e3 = (__expf(bs * acc[mt][3][r]) - 1.0f) * 32.f;
        C32[row * (N >> 2) + (col0 >> 2) + wn * 16 + ln] =
            f8pack4(e0, e1, e2, e3);
        float s = e0 + e1 + e2 + e3;
        s += __shfl_xor(s, 1, 64);
        s += __shfl_xor(s, 2, 64);
        s += __shfl_xor(s, 4, 64);
        s += __shfl_xor(s, 8, 64);
        if (ln == 0) atomicAdd(&rowsum_out[row], s);
      }
  } else {
    float* C = (float*)Cv;
#pragma unroll
    for (int mt = 0; mt < 4; ++mt)
#pragma unroll
      for (int r = 0; r < 4; ++r) {
        long row = row0 + wm * 64 + mt * 16 + quad * 4 + r;
        float inv = 1.0f / (8192.0f + rowsum[row] * (1.0f / 32.0f));
#pragma unroll
        for (int nt = 0; nt < 4; ++nt) {
          long col = col0 + wn * 64 + nt * 16 + ln;
          C[row * N + col] =
              (acc[mt][nt][r] * (1.0f / 1024.0f) + colsum[col]) * inv;
        }
      }
  }
}

// --------------------------- launch ----------------------------------------

extern "C" void kernel_launch(void* const* d_in, const int* in_sizes, int n_in,
                              void* d_out, int out_size, void* d_ws,
                              size_t ws_size, hipStream_t stream) {
  const float* x    = (const float*)d_in[0];
  const float* wq   = (const float*)d_in[1];
  const float* xi   = (const float*)d_in[2];
  const float* beta = (const float*)d_in[3];
  float* out = (float*)d_out;

  char* ws = (char*)d_ws;
  const size_t MB = 1024 * 1024;
  unsigned char* x8   = (unsigned char*)(ws);             //  8 MiB
  unsigned char* wq8  = (unsigned char*)(ws + 8 * MB);    //  1 MiB
  unsigned char* q8   = (unsigned char*)(ws + 9 * MB);    //  8 MiB
  unsigned char* xi8  = (unsigned char*)(ws + 17 * MB);   //  8 MiB
  unsigned char* xit8 = (unsigned char*)(ws + 25 * MB);   //  8 MiB
  float*         rs   = (float*)(ws + 33 * MB);           // 32 KiB
  float*         csum = (float*)(ws + 33 * MB + 32768);   //  4 KiB
  unsigned char* E8   = (unsigned char*)(ws + 34 * MB);   // 64 MiB

  hipMemsetAsync(rs, 0, 36864, stream);  // rs + colsum

  cast_f8<<<(NROW * NDIM / 4) / 256, 256, 0, stream>>>(
      x, (unsigned*)x8, 1.0f, NROW * NDIM / 4);
  cast_f8<<<(NDIM * NDIM / 4) / 256, 256, 0, stream>>>(
      wq, (unsigned*)wq8, 32.0f, NDIM * NDIM / 4);
  xi_prep8<<<dim3(NDIM / 32, NPAT / 32), dim3(32, 8), 0, stream>>>(
      xi, xi8, xit8, csum);

  // GEMM1: q = x @ wq^T (acc = 32q), store fp8(q) packed. 512 blocks.
  gemm_f8<0><<<dim3(NDIM / 128, NROW / 128), 256, 0, stream>>>(
      x8, wq8, q8, NDIM, NDIM, nullptr, nullptr, nullptr, nullptr);

  // GEMM2: F = 32*(exp(beta*q.xi)-1), fp8 packed + rowsums. 4096 blocks.
  gemm_f8<1><<<dim3(NPAT / 128, NROW / 128), 256, 0, stream>>>(
      q8, xi8, E8, NPAT, NDIM, beta, nullptr, nullptr, rs);

  // GEMM3: out = (colsum + F@xi/32) / (8192 + rowsum/32). 512 blocks.
  gemm_f8<2><<<dim3(NDIM / 128, NROW / 128), 256, 0, stream>>>(
      E8, xit8, out, NDIM, NPAT, nullptr, rs, csum, nullptr);
}